// Round 10
// baseline (253.395 us; speedup 1.0000x reference)
//
#include <hip/hip_runtime.h>

typedef __bf16 bf16x8 __attribute__((ext_vector_type(8)));
typedef __bf16 bf16x4 __attribute__((ext_vector_type(4)));
typedef float  f32x4  __attribute__((ext_vector_type(4)));

#define B_    4
#define S_    2048
#define E_    1024
#define H_    16
#define D_    64
#define MROWS (B_*S_)   // 8192

// log2(e) / sqrt(D) — folded into Q in the GEMM epilogue
#define SCORE_SCALE 0.18033688011112043f

__device__ __forceinline__ void load_lds16(const void* g, void* l) {
  __builtin_amdgcn_global_load_lds((__attribute__((address_space(1))) void*)g,
                                   (__attribute__((address_space(3))) void*)l,
                                   16, 0, 0);
}

__device__ __forceinline__ f32x4 mfma16(bf16x8 a, bf16x8 b, f32x4 c) {
  return __builtin_amdgcn_mfma_f32_16x16x32_bf16(a, b, c, 0, 0, 0);
}

// swizzled LDS element offset, 64-col bf16 rows: data chunk (8 elems) lands at
// physical chunk (dchunk ^ (row&7))  -> all fragment reads are <=2-way (free)
__device__ __forceinline__ int swz(int row, int dchunk) {
  return row * 64 + ((dchunk ^ (row & 7)) * 8);
}

// ---------------- fused prep: cvt_x | pack_w | pack_wo ----------------

__global__ void prep(const float4* __restrict__ x, const float* __restrict__ Wq,
                     const float* __restrict__ Wk, const float* __restrict__ Wv,
                     const float* __restrict__ bq, const float* __restrict__ bk,
                     const float* __restrict__ bv, const float* __restrict__ Wo,
                     __bf16* __restrict__ xb, __bf16* __restrict__ Wt,
                     float* __restrict__ bqkv, __bf16* __restrict__ Wot) {
  __shared__ float t[64][65];
  int bid = blockIdx.x;
  if (bid < 8192) {                      // cvt_x: fp32 x -> bf16
    int id = bid * 256 + threadIdx.x;
    float4 v = x[id];
    bf16x4 o = { (__bf16)v.x, (__bf16)v.y, (__bf16)v.z, (__bf16)v.w };
    *(bf16x4*)(xb + 4 * (size_t)id) = o;
    return;
  }
  int tx = threadIdx.x & 63;
  int ty = threadIdx.x >> 6;
  if (bid < 8960) {                      // pack_w: [H,E,D] -> Wt[3*H*D][E]
    int b2 = bid - 8192;                 // 768
    int e0 = (b2 & 15) * 64;
    int h  = (b2 >> 4) & 15;
    int p  = b2 >> 8;
    const float* W    = (p == 0) ? Wq : (p == 1) ? Wk : Wv;
    const float* bsrc = (p == 0) ? bq : (p == 1) ? bk : bv;
#pragma unroll
    for (int r = 0; r < 16; ++r) {
      int eL = ty + r * 4;
      t[eL][tx] = W[((size_t)h * 1024 + (e0 + eL)) * 64 + tx];
    }
    __syncthreads();
#pragma unroll
    for (int r = 0; r < 16; ++r) {
      int d = ty + r * 4;
      Wt[((size_t)(p * 1024 + h * 64 + d)) * 1024 + e0 + tx] = (__bf16)t[tx][d];
    }
    if ((b2 & 15) == 0 && threadIdx.x < 64)
      bqkv[p * 1024 + h * 64 + threadIdx.x] = bsrc[h * 64 + threadIdx.x];
  } else {                               // pack_wo: Wo[1024,1024] -> Wot[e][hd]
    int b2 = bid - 8960;                 // 256
    int hd0 = (b2 >> 4) * 64;
    int e0  = (b2 & 15) * 64;
#pragma unroll
    for (int r = 0; r < 16; ++r) {
      int hdL = ty + r * 4;
      t[hdL][tx] = Wo[(size_t)(hd0 + hdL) * 1024 + e0 + tx];
    }
    __syncthreads();
#pragma unroll
    for (int r = 0; r < 16; ++r) {
      int eL = ty + r * 4;
      Wot[(size_t)(e0 + eL) * 1024 + hd0 + tx] = (__bf16)t[tx][eL];
    }
  }
}

// ---- gemm8t: m201-faithful 8-phase 256x256 GEMM (QKV projection) -----------
// C[8192,3072] = A @ Bt^T + bias. BM=BN=256, BK=64, 16 K-tiles, 2/iter.
// 512 thr = 8 waves (2M x 4N); per-wave 128x64; acc[8][4]. LDS 128 KB
// (As 2x32K + Bs 2x32K; even tiles buf0, odd buf1) -> 1 block/CU.
//
// TEMPLATE-FAITHFUL phase (the piece both failed ports lacked):
//   { ds-reads for THIS phase's quadrant | 2 stage loads }  <- issued first
//   s_barrier                    <- ds_read latency hides under barrier skew
//   s_waitcnt lgkmcnt(0); sched_barrier
//   setprio(1); 16 MFMA (one C-quadrant, K=64); setprio(0)
//   [ph3/ph7 only: vmcnt(4); sched_barrier]
//   s_barrier
// Quadrants: ph0 (m0-3,n0-1) reads 12 | ph1 (m0-3,n2-3) reads 4 |
//            ph2 (m4-7,n0-1) reads 8  | ph3 (m4-7,n2-3) reads 0  (bfr live ph0-3)
//
// Staging ring, 2 loads/phase, quarter-tiles (1 load = 64 rows x 64 cols):
//   ph0-1: tile(2i+1).A -> buf1   ph2-3: tile(2i+2).B -> buf0
//   ph4-5: tile(2i+2).A -> buf0   ph6-7: tile(2i+3).B -> buf1
// Retire-proof: buf B reads end ph1 (B restage @ph2 ok), buf A reads end ph2
// (A restage @ph4 ok); buf1 symmetric at ph5/ph6. vmcnt ledger: at ph3 the
// outstanding set is {t(2i+1).B x4 [prologue/prev ph6-7], t(2i+1).A x4,
// t(2i+2).B x4} = 12 -> vmcnt(4) drains exactly tile 2i+1 (consumed ph4).
// At ph7: {t(2i+2).B, t(2i+2).A, t(2i+3).B} = 12 -> vmcnt(4) drains t(2i+2).
// Prologue {t0.A, t0.B, t1.B; vmcnt(4)} establishes the invariant. Last iter:
// c,d clamped (&15) -> dead restages into retired buffers, ledger exact.

__global__ __launch_bounds__(512, 1) void gemm8t(const __bf16* __restrict__ A,
                                                 const __bf16* __restrict__ Bt,
                                                 const float* __restrict__ bias,
                                                 __bf16* __restrict__ QKb,
                                                 __bf16* __restrict__ VT) {
  constexpr int K = 1024;
  __shared__ __attribute__((aligned(16))) __bf16 As[2 * 16384];
  __shared__ __attribute__((aligned(16))) __bf16 Bs[2 * 16384];

  int tid = threadIdx.x, wave = tid >> 6, lane = tid & 63;
  int quad = lane >> 4, cc = lane & 15;
  int nwg = (int)gridDim.x;
  int bid = (int)blockIdx.x;
  bid = (bid & 7) * (nwg >> 3) + (bid >> 3);   // XCD-bijective (384%8==0)
  int bm = bid / 12, bn = bid % 12;
  const __bf16* Abase = A + (size_t)bm * 256 * K;
  const __bf16* Bbase = Bt + (size_t)bn * 256 * K;
  int wrow = (wave >> 2) * 128;
  int wcol = (wave & 3) * 64;

  f32x4 acc[8][4];
#pragma unroll
  for (int m = 0; m < 8; ++m)
#pragma unroll
    for (int n = 0; n < 4; ++n) acc[m][n] = (f32x4){0.f, 0.f, 0.f, 0.f};

  int srl = tid >> 3;                    // staging row within quarter 0..63
  int sch = tid & 7;
  int scol = (sch ^ (srl & 7)) * 8;      // pre-swizzled source col

#define STAGE_A(t, q, buf)                                                     \
  load_lds16(Abase + (size_t)((q) * 64 + srl) * K + (t) * 64 + scol,           \
             &As[(buf) * 16384 + (q) * 4096 + tid * 8])
#define STAGE_B(t, q, buf)                                                     \
  load_lds16(Bbase + (size_t)((q) * 64 + srl) * K + (t) * 64 + scol,           \
             &Bs[(buf) * 16384 + (q) * 4096 + tid * 8])

  // prologue: t0 full (8), t1.B (4); vmcnt(4) -> t0 landed, t1.B in flight
#pragma unroll
  for (int q = 0; q < 4; ++q) STAGE_A(0, q, 0);
#pragma unroll
  for (int q = 0; q < 4; ++q) STAGE_B(0, q, 0);
#pragma unroll
  for (int q = 0; q < 4; ++q) STAGE_B(1, q, 1);
  asm volatile("s_waitcnt vmcnt(4)" ::: "memory");
  __builtin_amdgcn_sched_barrier(0);
  asm volatile("s_barrier" ::: "memory");

  bf16x8 af[4][2], bfr[4][2];

#define RD_A4(buf, mlo)                                                        \
  _Pragma("unroll") for (int m2 = 0; m2 < 4; ++m2)                             \
      _Pragma("unroll") for (int kk = 0; kk < 2; ++kk)                         \
          af[m2][kk] = *(const bf16x8*)&As[(buf) * 16384 +                     \
              swz(wrow + ((mlo) + m2) * 16 + cc, kk * 4 + quad)]
#define RD_B2(buf, nlo)                                                        \
  _Pragma("unroll") for (int n2 = 0; n2 < 2; ++n2)                             \
      _Pragma("unroll") for (int kk = 0; kk < 2; ++kk)                         \
          bfr[(nlo) + n2][kk] = *(const bf16x8*)&Bs[(buf) * 16384 +            \
              swz(wcol + ((nlo) + n2) * 16 + cc, kk * 4 + quad)]
#define MFMA_Q(mlo, nlo)                                                       \
  do {                                                                         \
    __builtin_amdgcn_s_setprio(1);                                             \
    _Pragma("unroll") for (int m2 = 0; m2 < 4; ++m2)                           \
        _Pragma("unroll") for (int n2 = 0; n2 < 2; ++n2)                       \
            _Pragma("unroll") for (int kk = 0; kk < 2; ++kk)                   \
                acc[(mlo) + m2][(nlo) + n2] =                                  \
                    mfma16(af[m2][kk], bfr[(nlo) + n2][kk],                    \
                           acc[(mlo) + m2][(nlo) + n2]);                       \
    __builtin_amdgcn_s_setprio(0);                                             \
  } while (0)
#define LGKM0                                                                  \
  asm volatile("s_waitcnt lgkmcnt(0)" ::: "memory");                           \
  __builtin_amdgcn_sched_barrier(0)
#define VMC4                                                                   \
  asm volatile("s_waitcnt vmcnt(4)" ::: "memory");                             \
  __builtin_amdgcn_sched_barrier(0)
#define BAR asm volatile("s_barrier" ::: "memory")

#pragma unroll 1
  for (int it = 0; it < 8; ++it) {
    int b1 = 2 * it + 1;
    int c_t = (2 * it + 2) & 15;         // clamped: dead restage on last iter
    int d_t = (2 * it + 3) & 15;
    // ---- tile a = 2it (buf0) ----
    // ph0
    RD_A4(0, 0); RD_B2(0, 0);
    STAGE_A(b1, 0, 1); STAGE_A(b1, 1, 1);
    BAR; LGKM0; MFMA_Q(0, 0); BAR;
    // ph1
    RD_B2(0, 2);
    STAGE_A(b1, 2, 1); STAGE_A(b1, 3, 1);
    BAR; LGKM0; MFMA_Q(0, 2); BAR;
    // ph2
    RD_A4(0, 4);
    STAGE_B(c_t, 0, 0); STAGE_B(c_t, 1, 0);
    BAR; LGKM0; MFMA_Q(4, 0); BAR;
    // ph3 (no reads)
    STAGE_B(c_t, 2, 0); STAGE_B(c_t, 3, 0);
    BAR; MFMA_Q(4, 2);
    VMC4; BAR;                           // tile b1 fully landed for all waves
    // ---- tile b = 2it+1 (buf1) ----
    // ph4
    RD_A4(1, 0); RD_B2(1, 0);
    STAGE_A(c_t, 0, 0); STAGE_A(c_t, 1, 0);
    BAR; LGKM0; MFMA_Q(0, 0); BAR;
    // ph5
    RD_B2(1, 2);
    STAGE_A(c_t, 2, 0); STAGE_A(c_t, 3, 0);
    BAR; LGKM0; MFMA_Q(0, 2); BAR;
    // ph6
    RD_A4(1, 4);
    STAGE_B(d_t, 0, 1); STAGE_B(d_t, 1, 1);
    BAR; LGKM0; MFMA_Q(4, 0); BAR;
    // ph7 (no reads)
    STAGE_B(d_t, 2, 1); STAGE_B(d_t, 3, 1);
    BAR; MFMA_Q(4, 2);
    VMC4; BAR;                           // tile c fully landed for next iter
  }
  asm volatile("s_waitcnt vmcnt(0)" ::: "memory");  // drain dead restages

  // epilogue (QKV split): cols<2048 -> QKb (Q pre-scaled); else VT
#pragma unroll
  for (int n = 0; n < 4; ++n) {
    int gcol = bn * 256 + wcol + n * 16 + cc;
    float bv = bias[gcol];
#pragma unroll
    for (int m = 0; m < 8; ++m) {
      int grow0 = bm * 256 + wrow + m * 16 + quad * 4;
      if (gcol < 2048) {
        float sc = (gcol < 1024) ? SCORE_SCALE : 1.0f;
#pragma unroll
        for (int r = 0; r < 4; ++r)
          QKb[(size_t)(grow0 + r) * 2048 + gcol] =
              (__bf16)((acc[m][n][r] + bv) * sc);
      } else {                           // V -> VT[(b*16+h)*64+d][s], packed x4
        int bh = (grow0 >> 11) * 16 + ((gcol >> 6) & 15);
        int d  = gcol & 63;
        bf16x4 pk;
#pragma unroll
        for (int r = 0; r < 4; ++r) pk[r] = (__bf16)(acc[m][n][r] + bv);
        *(bf16x4*)&VT[((size_t)(bh * 64 + d)) * 2048 + (grow0 & 2047)] = pk;
      }
    }
  }
#undef STAGE_A
#undef STAGE_B
#undef RD_A4
#undef RD_B2
#undef MFMA_Q
#undef LGKM0
#undef VMC4
#undef BAR
}

// ------- 8-phase GEMM, BM=128, 2 blocks/CU (R6-proven) — output proj --------

template <int MODE, int BN, int NDIM>
__global__ __launch_bounds__(512, 4) void gemm8h(const __bf16* __restrict__ A,
                                                 const __bf16* __restrict__ Bt,
                                                 const float* __restrict__ bias,
                                                 void* __restrict__ Cout,
                                                 __bf16* __restrict__ VT) {
  constexpr int K = 1024;
  constexpr int NB = BN / 64;
  constexpr int WC = BN / 4;
  __shared__ __attribute__((aligned(16))) __bf16 As[2 * 128 * 64];
  __shared__ __attribute__((aligned(16))) __bf16 Bs[2 * BN * 64];

  int tid = threadIdx.x, wave = tid >> 6, lane = tid & 63;
  int quad = lane >> 4, cc = lane & 15;
  constexpr int nb = NDIM / BN;
  int nwg = (int)gridDim.x;
  int bid = (int)blockIdx.x;
  bid = (bid & 7) * (nwg >> 3) + (bid >> 3);
  int bm = bid / nb, bn = bid % nb;
  const __bf16* Abase = A + (size_t)bm * 128 * K;
  const __bf16* Bbase = Bt + (size_t)bn * BN * K;
  int wrow = (wave >> 2) * 64;
  int wcol = (wave & 3) * WC;

  f32x4 acc[4][NB];
#pragma unroll
  for (int m = 0; m < 4; ++m)
#pragma unroll
    for (int n = 0; n < NB; ++n) acc[m][n] = (f32x4){0.f, 0.f, 0.f, 0.f};

  int srl = tid >> 3;
  int sch = tid & 7;
  int scol = (sch ^ (srl & 7)) * 8;

#define STAGE_A(t, sub, buf)                                                   \
  load_lds16(Abase + (size_t)((sub) * 64 + srl) * K + (t) * 64 + scol,         \
             &As[(buf) * 8192 + (sub) * 4096 + tid * 8])
#define STAGE_B(t, sub, buf)                                                   \
  load_lds16(Bbase + (size_t)((sub) * 64 + srl) * K + (t) * 64 + scol,         \
             &Bs[(buf) * (BN * 64) + (sub) * 4096 + tid * 8])

#pragma unroll
  for (int s = 0; s < 2; ++s) STAGE_A(0, s, 0);
#pragma unroll
  for (int s = 0; s < NB; ++s) STAGE_B(0, s, 0);
#pragma unroll
  for (int s = 0; s < 2; ++s) STAGE_A(1, s, 1);
  asm volatile("s_waitcnt vmcnt(2)" ::: "memory");
  __builtin_amdgcn_sched_barrier(0);
  asm volatile("s_barrier" ::: "memory");

  bf16x8 af[4][2], bfr[NB][2];

#define RD_B(buf)                                                              \
  _Pragma("unroll") for (int n = 0; n < NB; ++n)                               \
      _Pragma("unroll") for (int kk = 0; kk < 2; ++kk)                         \
          bfr[n][kk] = *(const bf16x8*)&Bs[(buf) * (BN * 64) +                 \
                                           swz(wcol + n * 16 + cc, kk * 4 + quad)]
#define RD_A2(buf, mlo)                                                        \
  _Pragma("unroll") for (int m = mlo; m < (mlo) + 2; ++m)                      \
      _Pragma("unroll") for (int kk = 0; kk < 2; ++kk)                         \
          af[m][kk] = *(const bf16x8*)&As[(buf) * 8192 +                       \
                                          swz(wrow + m * 16 + cc, kk * 4 + quad)]
#define MFMA_M(m)                                                              \
  do {                                                                         \
    __builtin_amdgcn_s_setprio(1);                                             \
    _Pragma("unroll") for (int n = 0; n < NB; ++n)                             \
        _Pragma("unroll") for (int kk = 0; kk < 2; ++kk)                       \
            acc[m][n] = mfma16(af[m][kk], bfr[n][kk], acc[m][n]);              \
    __builtin_amdgcn_s_setprio(0);                                             \
  } while (0)
#define LGKM0                                                                  \
  asm volatile("s_waitcnt lgkmcnt(0)" ::: "memory");                           \
  __builtin_amdgcn_sched_barrier(0)
#define VMC2                                                                   \
  asm volatile("s_waitcnt vmcnt(2)" ::: "memory");                             \
  __builtin_amdgcn_sched_barrier(0)
#define BAR asm volatile("s_barrier" ::: "memory")

#pragma unroll 1
  for (int it = 0; it < 8; ++it) {
    int b_t = 2 * it + 1;
    int c_t = (2 * it + 2) & 15;
    int d_t = (2 * it + 3) & 15;
    RD_B(0); RD_A2(0, 0);
    STAGE_B(b_t, 0, 1); STAGE_B(b_t, 1, 1);
    LGKM0; MFMA_M(0); BAR;
    RD_A2(0, 2);
    if (NB >= 3) STAGE_B(b_t, 2, 1);
    LGKM0; MFMA_M(1); BAR;
    STAGE_A(c_t, 0, 0); STAGE_A(c_t, 1, 0);
    MFMA_M(2); BAR;
    MFMA_M(3);
    VMC2; BAR;
    RD_B(1); RD_A2(1, 0);
    STAGE_B(c_t, 0, 0); STAGE_B(c_t, 1, 0);
    LGKM0; MFMA_M(0); BAR;
    RD_A2(1, 2);
    if (NB >= 3) STAGE_B(c_t, 2, 0);
    LGKM0; MFMA_M(1); BAR;
    STAGE_A(d_t, 0, 1); STAGE_A(d_t, 1, 1);
    MFMA_M(2); BAR;
    MFMA_M(3);
    VMC2; BAR;
  }
  asm volatile("s_waitcnt vmcnt(0)" ::: "memory");

#pragma unroll
  for (int n = 0; n < NB; ++n) {
    int gcol = bn * BN + wcol + n * 16 + cc;
    float bv = bias[gcol];
#pragma unroll
    for (int m = 0; m < 4; ++m) {
      int grow0 = bm * 128 + wrow + m * 16 + quad * 4;
      if (MODE == 0) {
#pragma unroll
        for (int r = 0; r < 4; ++r)
          ((float*)Cout)[(size_t)(grow0 + r) * NDIM + gcol] = acc[m][n][r] + bv;
      } else if (gcol < 2048) {
        float sc = (gcol < 1024) ? SCORE_SCALE : 1.0f;
#pragma unroll
        for (int r = 0; r < 4; ++r)
          ((__bf16*)Cout)[(size_t)(grow0 + r) * 2048 + gcol] =
              (__bf16)((acc[m][n][r] + bv) * sc);
      } else {
        int bh = (grow0 >> 11) * 16 + ((gcol >> 6) & 15);
        int d  = gcol & 63;
        bf16x4 pk;
#pragma unroll
        for (int r = 0; r < 4; ++r) pk[r] = (__bf16)(acc[m][n][r] + bv);
        *(bf16x4*)&VT[((size_t)(bh * 64 + d)) * 2048 + (grow0 & 2047)] = pk;
      }
    }
  }
#undef STAGE_A
#undef STAGE_B
#undef RD_B
#undef RD_A2
#undef MFMA_M
#undef LGKM0
#undef VMC2
#undef BAR
}

// ---------------- causal flash attention — 40KB LDS (R9, best) --------------

__global__ __launch_bounds__(256, 4) void attn(const __bf16* __restrict__ QKb,
                                               const __bf16* __restrict__ VT,
                                               __bf16* __restrict__ O) {
  int bx = blockIdx.x;
  int bh = bx & 63;
  int g  = bx >> 6;                           // 0..15
  int qt = (g < 8) ? (15 - g) : (g - 8);
  int h  = bh & 15;
  int b  = bh >> 4;
  int q0 = qt * 128;
  int tid = threadIdx.x, wave = tid >> 6, lane = tid & 63;
  int quad = lane >> 4, c = lane & 15;

  __shared__ __attribute__((aligned(16))) __bf16 smem[20480];
  __bf16* Ps = smem + wave * 1024;
  __bf16* Ks = smem + 4096;
  __bf16* Vs = smem + 12288;

  const __bf16* Vbase = VT + (size_t)bh * (64 * 2048);
  int qwave = q0 + wave * 32;

  bf16x8 qf[2][2];
#pragma unroll
  for (int i = 0; i < 2; ++i)
#pragma unroll
    for (int kk = 0; kk < 2; ++kk)
      qf[i][kk] = *(const bf16x8*)&QKb[(size_t)(b * S_ + qwave + i * 16 + c) * 2048 +
                                       h * 64 + (kk * 4 + quad) * 8];

  {
    const __bf16* Kb = QKb + (size_t)(b * S_) * 2048 + 1024 + h * 64;
#pragma unroll
    for (int p = 0; p < 2; ++p) {
      int gi = tid + p * 256;
      int row = gi >> 3, pch = gi & 7;
      load_lds16(Kb + (size_t)row * 2048 + (pch ^ (row & 7)) * 8, &Ks[gi * 8]);
      load_lds16(Vbase + (size_t)row * 2048 + (pch ^ (row & 7)) * 8, &Vs[gi * 8]);
    }
  }
  __syncthreads();

  const __bf16 one_b = (__bf16)1.0f;
  bf16x8 ones = { one_b, one_b, one_b, one_b, one_b, one_b, one_b, one_b };

  f32x4 acc_o[2][4], acc_l[2];
#pragma unroll
  for (int i = 0; i < 2; ++i) {
    acc_l[i] = (f32x4){0.f, 0.f, 0.f, 0.f};
#pragma unroll
    for (int j = 0; j < 4; ++j) acc_o[i][j] = (f32x4){0.f, 0.f, 0.f, 0.f};
  }

  int ntiles = qt * 2 + 2;
  for (int t = 0; t < ntiles; ++t) {
    int cur = t & 1;
    if (t + 1 < ntiles) {
      int kv1 = (t + 1) * 64;
      const __bf16* Kb = QKb + (size_t)(b * S_ + kv1) * 2048 + 1024 + h * 64;
      const __bf16* Vb = Vbase + kv1;
#pragma unroll
      for (int p = 0; p < 2; ++p) {
        int gi = tid + p * 256;
        int row = gi >> 3, pch = gi & 7;
        load_lds16(Kb + (size_t)row * 2048 + (pch ^ (row & 7)) * 8,
                   &Ks[(cur ^ 1) * 4096 + gi * 8]);
        load_lds16(Vb + (size_t)row * 2048 + (pch ^ (row & 7)) * 8,
                   &Vs[(cur ^ 1) * 4096 + gi * 8]);
      }
      asm volatile("s_waitcnt vmcnt(4)" ::: "memory");
    } else {
      asm volatile("s_waitcnt vmcnt(0)" ::: "memory");
    }
    __builtin_amdgcn_sched_barrier(0);
    asm volatile("s_barrier" ::: "memory");

    int kv0 = t * 64;
    if (kv0 <= qwave + 31) {
      const __bf16* Kc = Ks + cur * 4096;
      const __bf16* Vc = Vs + cur * 4096;

      f32x4 acc_t[2][4];
#pragma unroll
      for (int i = 0; i < 2; ++i)
#pragma unroll
        for (int j = 0; j < 4; ++j) acc_t[i][j] = (f32x4){0.f, 0.f, 0.f, 0.f};
      bf16x8 kf[4][2];
#pragma unroll
      for (int j = 0; j < 4; ++j)
#pragma unroll
        for (int kk = 0; kk < 2; ++kk)
          kf[j][kk] = *(const bf16x8*)&Kc[swz(j * 16 + c, kk * 4 + quad)];
      __builtin_amdgcn_s_setprio(1);
#pragma unroll
      for (int i = 0; i < 2; ++i)
#pragma unroll
        for (int j = 0; j < 4; ++j)
#pragma unroll
          for (int kk = 0; kk < 2; ++kk)
            acc_t[i][j] = mfma16(kf[j][kk], qf[i][kk], acc_t[i][j]);
      __builtin_amdgcn_s_setprio(0);

      bool domask = (kv0 + 63 > qwave);
      bf16x8 pf[2][2];
#pragma unroll
      for (int i = 0; i < 2; ++i) {
        int q_g = qwave + i * 16 + c;
#pragma unroll
        for (int j = 0; j < 4; ++j) {
          bf16x4 pk;
#pragma unroll
          for (int r = 0; r < 4; ++r) {
            float p = __builtin_amdgcn_exp2f(acc_t[i][j][r]);
            if (domask) {
              int kv = kv0 + j * 16 + quad * 4 + r;
              p = (kv > q_g) ? 0.f : p;
            }
            pk[r] = (__bf16)p;
          }
          int dch8 = j * 2 + (quad >> 1);
          int phys = c * 64 + ((dch8 ^ (c & 7)) * 8) + (quad & 1) * 4;
          *(bf16x4*)&Ps[phys] = pk;
        }
#pragma unroll
        for (int kk = 0; kk < 2; ++kk)
          pf[i][kk] = *(const bf16x8*)&Ps[swz(c, kk * 4 + quad)];
      }

      bf16x8 vf[4][2];
#pragma unroll
      for (int j = 0; j < 4; ++j)
#pragma unroll
        for (int kk = 0; kk < 2; ++kk)
          vf[j][kk] = *(const bf16x8*)&Vc[swz(j * 16 + c, kk * 4 + quad)];
      __builtin_amdgcn_s_setprio(1);
#pragma unroll
      for (int i = 0; i < 2; ++i) {
#pragma unroll
        for (int j = 0; j < 4; ++j)
#pragma unroll
          for (int kk = 0; kk < 2; ++kk)
            acc_o[i][j] = mfma16(pf[i][kk], vf[j][kk], acc_o[i][j]);
        acc_l[i] = mfma16(pf[i][0], ones, acc_l[i]);
        acc_l[i] = mfma16(pf[i][1], ones, acc_l[i]);
      }
      __builtin_amdgcn_s_setprio(0);
    }

    asm volatile("s_barrier" ::: "memory");
  }

  __bf16* Obase = O + (size_t)(b * S_ + q0) * 1024 + h * 64;
#pragma unroll
  for (int i = 0; i < 2; ++i)
#pragma unroll
    for (int r = 0; r < 4; ++r) {
      float rl = 1.0f / acc_l[i][r];
      int row = wave * 32 + i * 16 + quad * 4 + r;
#pragma unroll
      for (int j = 0; j < 4; ++j)
        Obase[(size_t)row * 1024 + j * 16 + c] = (__bf16)(acc_o[i][j][r] * rl);
    }
}

// ---------------- launcher ----------------

extern "C" void kernel_launch(void* const* d_in, const int* in_sizes, int n_in,
                              void* d_out, int out_size, void* d_ws, size_t ws_size,
                              hipStream_t stream) {
  (void)in_sizes; (void)n_in; (void)out_size; (void)ws_size;
  const float* x  = (const float*)d_in[0];
  const float* Wq = (const float*)d_in[1];
  const float* bq = (const float*)d_in[2];
  const float* Wk = (const float*)d_in[3];
  const float* bk = (const float*)d_in[4];
  const float* Wv = (const float*)d_in[5];
  const float* bv = (const float*)d_in[6];
  const float* Wo = (const float*)d_in[7];
  const float* bo = (const float*)d_in[8];

  char* w = (char*)d_ws;
  __bf16* xb   = (__bf16*)(w);                         // 16 MB
  __bf16* Wt   = (__bf16*)(w + (16ull << 20));         //  6 MB
  __bf16* Wot  = (__bf16*)(w + (22ull << 20));         //  2 MB
  float*  bqkv = (float*) (w + (24ull << 20));         // 12 KB
  __bf16* QKb  = (__bf16*)(w + (25ull << 20));         // 32 MB (Q|K, stride 2048)
  __bf16* Ob   = (__bf16*)(w + (57ull << 20));         // 16 MB
  __bf16* VT   = (__bf16*)(w + (73ull << 20));         // 16 MB (total 89 MB)

  prep<<<9216, 256, 0, stream>>>((const float4*)x, Wq, Wk, Wv, bq, bk, bv, Wo,
                                 xb, Wt, bqkv, Wot);
  gemm8t<<<384, 512, 0, stream>>>(xb, Wt, bqkv, QKb, VT);
  attn<<<1024, 256, 0, stream>>>(QKb, VT, Ob);
  gemm8h<0, 128, 1024><<<512, 512, 0, stream>>>(Ob, Wot, bo, d_out, nullptr);
}